// Round 10
// baseline (298.503 us; speedup 1.0000x reference)
//
#include <hip/hip_runtime.h>

#define NTOK   8192
#define DMODEL 1024
#define NC     64
#define NK     16
#define NP     64
#define NM     128
#define LCAP   (1 << 18)
#define MARGIN 2e-3f

typedef _Float16 f16x8  __attribute__((ext_vector_type(8)));
typedef float    f32x16 __attribute__((ext_vector_type(16)));

#define AS1 __attribute__((address_space(1)))
#define AS3 __attribute__((address_space(3)))

__device__ __forceinline__ void glds16(const void* g, void* l) {
    __builtin_amdgcn_global_load_lds((const AS1 void*)g, (AS3 void*)l, 16, 0, 0);
}

// ------------------------------------------------------------------
// Kernel 0: split x, W_A, W_B into fp16 hi/lo with subtiled layout
// [k/8][row][8] so the GEMM stages via linear global_load_lds.
// ------------------------------------------------------------------
__global__ __launch_bounds__(256) void k_split(
    const float* __restrict__ x, const float* __restrict__ W_A, const float* __restrict__ W_B,
    short* __restrict__ xh, short* __restrict__ xl,
    short* __restrict__ whA, short* __restrict__ wlA,
    short* __restrict__ whB, short* __restrict__ wlB)
{
    const int t = blockIdx.x * 256 + threadIdx.x;
    const int NX = 128 * NTOK;            // 1048576 units
    const int NW = 128 * 1024;            // 131072 units

    const float* src;
    short *dh, *dl;
    if (t < NX) {
        const int chunk = t >> 13, tok = t & 8191;
        src = x + (size_t)tok * DMODEL + chunk * 8;
        dh = xh + (size_t)t * 8;  dl = xl + (size_t)t * 8;
    } else if (t < NX + NW) {
        const int u = t - NX, chunk = u >> 10, ck = u & 1023;
        src = W_A + (size_t)ck * DMODEL + chunk * 8;
        dh = whA + (size_t)u * 8; dl = wlA + (size_t)u * 8;
    } else {
        const int u = t - NX - NW, chunk = u >> 10, ck = u & 1023;
        src = W_B + (size_t)ck * DMODEL + chunk * 8;
        dh = whB + (size_t)u * 8; dl = wlB + (size_t)u * 8;
    }

    const float4 a = *(const float4*)src;
    const float4 b = *(const float4*)(src + 4);
    const float v[8] = {a.x, a.y, a.z, a.w, b.x, b.y, b.z, b.w};
    unsigned h[8], l[8];
    #pragma unroll
    for (int j = 0; j < 8; ++j) {
        const _Float16 hf = (_Float16)v[j];
        const _Float16 lf = (_Float16)(v[j] - (float)hf);
        h[j] = (unsigned)__builtin_bit_cast(unsigned short, hf);
        l[j] = (unsigned)__builtin_bit_cast(unsigned short, lf);
    }
    *(int4*)dh = make_int4((int)(h[0] | (h[1] << 16)), (int)(h[2] | (h[3] << 16)),
                           (int)(h[4] | (h[5] << 16)), (int)(h[6] | (h[7] << 16)));
    *(int4*)dl = make_int4((int)(l[0] | (l[1] << 16)), (int)(l[2] | (l[3] << 16)),
                           (int)(l[4] | (l[5] << 16)), (int)(l[6] | (l[7] << 16)));
}

// ------------------------------------------------------------------
// Kernel 1: fp16x3 MFMA GEMM + MFMA-based d2 scoring + argmin.
// Main loop: round-9 structure (reg prefetch, 4 LDS bufs, BK=16).
// Epilogue: proj -> fp16 hi/lo in LDS as scoring-B fragments
// ([cb2][tok] 16B chunks, XOR-swizzled); per codebook the wave holds
// A = (-2 emb) fp16 hi/lo frags + C-init = e2[p]; one MFMA chain per
// 32-token group gives g[p][tok] directly; in-register top-2 argmin.
// ------------------------------------------------------------------
struct Frags { f16x8 ah[4], al[4], bh[2], bl[2]; };

__device__ __forceinline__ void load_frags(Frags& f, const short* bb,
                                           int aoff, int boff) {
    #pragma unroll
    for (int m = 0; m < 4; ++m) {
        f.ah[m] = *(const f16x8*)(bb + aoff + m * 256);
        f.al[m] = *(const f16x8*)(bb + 4096 + aoff + m * 256);
    }
    #pragma unroll
    for (int n = 0; n < 2; ++n) {
        f.bh[n] = *(const f16x8*)(bb + boff + n * 256);
        f.bl[n] = *(const f16x8*)(bb + 4096 + boff + n * 256);
    }
}

__device__ __forceinline__ void do_mfma(f32x16 acc[4][2], const Frags& f) {
    #pragma unroll
    for (int m = 0; m < 4; ++m)
        #pragma unroll
        for (int n = 0; n < 2; ++n)
            acc[m][n] = __builtin_amdgcn_mfma_f32_32x32x16_f16(f.ah[m], f.bh[n], acc[m][n], 0, 0, 0);
    #pragma unroll
    for (int m = 0; m < 4; ++m)
        #pragma unroll
        for (int n = 0; n < 2; ++n)
            acc[m][n] = __builtin_amdgcn_mfma_f32_32x32x16_f16(f.ah[m], f.bl[n], acc[m][n], 0, 0, 0);
    #pragma unroll
    for (int m = 0; m < 4; ++m)
        #pragma unroll
        for (int n = 0; n < 2; ++n)
            acc[m][n] = __builtin_amdgcn_mfma_f32_32x32x16_f16(f.al[m], f.bh[n], acc[m][n], 0, 0, 0);
}

__global__ __launch_bounds__(512, 1) void k_mfma_argmin(
    const short* __restrict__ xh, const short* __restrict__ xl,
    const short* __restrict__ whA, const short* __restrict__ wlA,
    const short* __restrict__ whB, const short* __restrict__ wlB,
    const float* __restrict__ emb_A, const float* __restrict__ emb_B,
    int* __restrict__ idxbuf, int* __restrict__ list, int* __restrict__ cnt)
{
    __shared__ __align__(16) float smem[32768];   // 128 KB
    short* ls = (short*)smem;

    const int tid = threadIdx.x;
    const int bid = blockIdx.x;
    const int swz = (bid & 7) * 32 + (bid >> 3);
    const int tb  = swz >> 3;              // token block 0..31 (256 tokens)
    const int ot  = swz & 7;               // out tile 0..7 (256 cols)
    const int set = ot >> 2;
    const short* __restrict__ wh = set ? whB : whA;
    const short* __restrict__ wl = set ? wlB : wlA;
    const float* __restrict__ Ep = set ? emb_B : emb_A;
    const int ckbase = (ot & 3) * 256;     // 16 codebooks x 16 k

    const int lane = tid & 63;
    const int wid  = tid >> 6;
    const int wr   = wid >> 2;             // M half 0..1 (128 tokens)
    const int wc   = wid & 3;              // N quarter 0..3 (64 cols)
    const int l31  = lane & 31;
    const int lk2  = lane >> 5;

    f32x16 acc[4][2];
    #pragma unroll
    for (int m = 0; m < 4; ++m)
        #pragma unroll
        for (int n = 0; n < 2; ++n)
            #pragma unroll
            for (int r = 0; r < 16; ++r) acc[m][n][r] = 0.f;

    // staging: per tile 4 glds16/thread. unit: chunk = tid>>8 (0..1), row = tid&255
    const size_t oA = ((size_t)(tid >> 8) * NTOK + tb * 256 + (tid & 255)) * 8;
    const size_t oB = ((size_t)(tid >> 8) * 1024 + ckbase + (tid & 255)) * 8;

    #define STAGE(buf, st)                                                   \
        do {                                                                 \
            const size_t sa_ = (size_t)(st) * (size_t)(2 * NTOK * 8);        \
            const size_t sb_ = (size_t)(st) * (size_t)(2 * 1024 * 8);        \
            short* lb_ = ls + (buf) * 16384 + tid * 8;                       \
            glds16(xh + oA + sa_, lb_);                                      \
            glds16(xl + oA + sa_, lb_ + 4096);                               \
            glds16(wh + oB + sb_, lb_ + 8192);                               \
            glds16(wl + oB + sb_, lb_ + 12288);                              \
        } while (0)

    const int aoff = (lk2 * 256 + wr * 128 + l31) * 8;
    const int boff = 8192 + (lk2 * 256 + wc * 64 + l31) * 8;

    Frags fE, fO;

    STAGE(0, 0);
    STAGE(1, 1);
    STAGE(2, 2);
    STAGE(3, 3);
    asm volatile("s_waitcnt vmcnt(12)" ::: "memory");
    __builtin_amdgcn_s_barrier();
    __builtin_amdgcn_sched_barrier(0);
    load_frags(fE, ls, aoff, boff);

    #define BODY(T, CUR, NXT)                                                \
        do {                                                                 \
            asm volatile("s_waitcnt vmcnt(8)" ::: "memory");                 \
            asm volatile("s_waitcnt lgkmcnt(0)" ::: "memory");               \
            __builtin_amdgcn_sched_barrier(0);                               \
            __builtin_amdgcn_s_barrier();                                    \
            __builtin_amdgcn_sched_barrier(0);                               \
            load_frags(NXT, ls + (((T) + 1) & 3) * 16384, aoff, boff);       \
            { const int ts_ = ((T) + 4 < 64) ? (T) + 4 : 63;                 \
              STAGE((T) & 3, ts_); }                                         \
            __builtin_amdgcn_s_setprio(1);                                   \
            do_mfma(acc, CUR);                                               \
            __builtin_amdgcn_s_setprio(0);                                   \
        } while (0)

    for (int t = 0; t < 62; t += 2) {
        BODY(t, fE, fO);
        BODY(t + 1, fO, fE);
    }
    BODY(62, fE, fO);
    asm volatile("s_waitcnt lgkmcnt(0)" ::: "memory");
    __builtin_amdgcn_sched_barrier(0);
    __builtin_amdgcn_s_barrier();
    __builtin_amdgcn_s_setprio(1);
    do_mfma(acc, fO);
    __builtin_amdgcn_s_setprio(0);
    #undef BODY
    #undef STAGE

    // drain outstanding staging loads before smem reuse
    asm volatile("s_waitcnt vmcnt(0)" ::: "memory");
    __builtin_amdgcn_s_barrier();

    // ---- epilogue: MFMA scoring + argmin, two 8-codebook halves ----
    // projB LDS layout (per half): 16B chunk sw = ((cb2<<8)+tok) ^ (cb2&7),
    // cb2 = cbH*2 + kh; hi at shorts [0,32768), lo at [32768, 65536).
    for (int h = 0; h < 2; ++h) {
        const int cbH = wid;                               // wave's codebook 0..7
        const int cbG = (ot & 3) * 16 + h * 8 + cbH;       // global codebook

        // emb prep (registers only; overlaps other waves' LDS writes)
        float ev0[8], ev1[8];
        {
            const float4* q0 = (const float4*)(Ep + ((size_t)(cbG * NP + l31) * NK + lk2 * 8));
            const float4* q1 = (const float4*)(Ep + ((size_t)(cbG * NP + 32 + l31) * NK + lk2 * 8));
            const float4 a0 = q0[0], b0 = q0[1], a1 = q1[0], b1 = q1[1];
            ev0[0]=a0.x; ev0[1]=a0.y; ev0[2]=a0.z; ev0[3]=a0.w;
            ev0[4]=b0.x; ev0[5]=b0.y; ev0[6]=b0.z; ev0[7]=b0.w;
            ev1[0]=a1.x; ev1[1]=a1.y; ev1[2]=a1.z; ev1[3]=a1.w;
            ev1[4]=b1.x; ev1[5]=b1.y; ev1[6]=b1.z; ev1[7]=b1.w;
        }
        float p20 = 0.f, p21 = 0.f;
        #pragma unroll
        for (int j = 0; j < 8; ++j) {
            p20 = fmaf(ev0[j], ev0[j], p20);
            p21 = fmaf(ev1[j], ev1[j], p21);
        }
        const float e20 = p20 + __shfl_xor(p20, 32);
        const float e21 = p21 + __shfl_xor(p21, 32);
        f16x8 A0h, A0l, A1h, A1l;
        #pragma unroll
        for (int j = 0; j < 8; ++j) {
            const float v0 = -2.f * ev0[j];
            const _Float16 h0 = (_Float16)v0;
            A0h[j] = h0; A0l[j] = (_Float16)(v0 - (float)h0);
            const float v1 = -2.f * ev1[j];
            const _Float16 h1 = (_Float16)v1;
            A1h[j] = h1; A1l[j] = (_Float16)(v1 - (float)h1);
        }
        f32x16 gi0, gi1;
        #pragma unroll
        for (int r = 0; r < 16; ++r) {
            const int cr = (r & 3) + 8 * (r >> 2);
            gi0[r] = __shfl(e20, cr + 4 * lk2);
            gi1[r] = __shfl(e21, cr + 4 * lk2);
        }

        __syncthreads();
        if ((wc >> 1) == h) {   // this wave's cols belong to half h: write projB
            #pragma unroll
            for (int m = 0; m < 4; ++m)
                #pragma unroll
                for (int n = 0; n < 2; ++n)
                    #pragma unroll
                    for (int r = 0; r < 16; ++r) {
                        const int colh = (wc & 1) * 64 + n * 32 + l31;
                        const int cb2  = ((colh >> 4) << 1) + ((colh >> 3) & 1);
                        const int kj   = colh & 7;
                        const int tok  = wr * 128 + m * 32 + (r & 3) + 8 * (r >> 2) + 4 * lk2;
                        const int sw   = ((cb2 << 8) + tok) ^ (cb2 & 7);
                        const float v  = acc[m][n][r];
                        const _Float16 hf = (_Float16)v;
                        ls[sw * 8 + kj]         = __builtin_bit_cast(short, hf);
                        ls[32768 + sw * 8 + kj] = __builtin_bit_cast(short, (_Float16)(v - (float)hf));
                    }
        }
        __syncthreads();

        for (int grp = 0; grp < 8; ++grp) {
            const int cb2 = cbH * 2 + lk2;
            const int sw8 = (((cb2 << 8) + grp * 32 + l31) ^ (cb2 & 7)) * 8;
            const f16x8 Bh = *(const f16x8*)(ls + sw8);
            const f16x8 Bl = *(const f16x8*)(ls + 32768 + sw8);
            f32x16 s0 = gi0, s1 = gi1;
            s0 = __builtin_amdgcn_mfma_f32_32x32x16_f16(A0h, Bh, s0, 0, 0, 0);
            s0 = __builtin_amdgcn_mfma_f32_32x32x16_f16(A0h, Bl, s0, 0, 0, 0);
            s0 = __builtin_amdgcn_mfma_f32_32x32x16_f16(A0l, Bh, s0, 0, 0, 0);
            s1 = __builtin_amdgcn_mfma_f32_32x32x16_f16(A1h, Bh, s1, 0, 0, 0);
            s1 = __builtin_amdgcn_mfma_f32_32x32x16_f16(A1h, Bl, s1, 0, 0, 0);
            s1 = __builtin_amdgcn_mfma_f32_32x32x16_f16(A1l, Bh, s1, 0, 0, 0);

            float best = 1e30f, second = 1e30f;
            int bp = 0;
            #pragma unroll
            for (int r = 0; r < 16; ++r) {
                const int cr = (r & 3) + 8 * (r >> 2);
                const float g = s0[r];
                const int p = cr + 4 * lk2;
                if (g < best) { second = best; best = g; bp = p; }
                else if (g < second) { second = g; }
            }
            #pragma unroll
            for (int r = 0; r < 16; ++r) {
                const int cr = (r & 3) + 8 * (r >> 2);
                const float g = s1[r];
                const int p = 32 + cr + 4 * lk2;
                if (g < best) { second = best; best = g; bp = p; }
                else if (g < second) { second = g; }
            }
            const float ob = __shfl_xor(best, 32);
            const float os = __shfl_xor(second, 32);
            const int   op = __shfl_xor(bp, 32);
            if (ob < best) { second = fminf(best, os); best = ob; bp = op; }
            else           { second = fminf(second, ob); }

            if (lane < 32) {
                const int tokG = tb * 256 + grp * 32 + lane;
                idxbuf[(set * NC + cbG) * NTOK + tokG] = bp;
                if (second - best < MARGIN) {
                    const int slot = atomicAdd(cnt, 1);
                    if (slot < LCAP) list[slot] = (set << 19) | (cbG << 13) | tokG;
                }
            }
        }
    }
}

// ------------------------------------------------------------------
// Kernel 2: fp64 exact re-resolution of flagged near-tie argmins.
// ------------------------------------------------------------------
__global__ __launch_bounds__(256) void k_refine(
    const float* __restrict__ x,
    const float* __restrict__ W_A, const float* __restrict__ W_B,
    const float* __restrict__ emb_A, const float* __restrict__ emb_B,
    const int* __restrict__ list, const int* __restrict__ cnt,
    int* __restrict__ idxbuf)
{
    int n = *cnt;
    if (n > LCAP) n = LCAP;
    const int lane = threadIdx.x & 63;
    const int wave = (int)((blockIdx.x * blockDim.x + threadIdx.x) >> 6);
    const int nw   = (int)((gridDim.x * blockDim.x) >> 6);

    for (int i = wave; i < n; i += nw) {
        const int code = list[i];
        const int tok = code & 8191;
        const int c   = (code >> 13) & 63;
        const int set = (code >> 19) & 1;
        const float* __restrict__ Wp = set ? W_B : W_A;
        const float* __restrict__ Ep = set ? emb_B : emb_A;

        double pk[16];
        #pragma unroll
        for (int k = 0; k < 16; ++k) pk[k] = 0.0;
        for (int dd = 0; dd < 16; ++dd) {
            const int d = dd * 64 + lane;
            const double xv = (double)x[(size_t)tok * DMODEL + d];
            #pragma unroll
            for (int k = 0; k < 16; ++k)
                pk[k] = fma(xv, (double)Wp[(size_t)(c * 16 + k) * DMODEL + d], pk[k]);
        }
        #pragma unroll
        for (int k = 0; k < 16; ++k) {
            #pragma unroll
            for (int off = 32; off; off >>= 1)
                pk[k] += __shfl_xor(pk[k], off, 64);
        }
        double d2 = 0.0;
        #pragma unroll
        for (int k = 0; k < 16; ++k) {
            const double t = pk[k] - (double)Ep[(size_t)(c * NP + lane) * NK + k];
            d2 = fma(t, t, d2);
        }
        int bp = lane;
        double bv = d2;
        #pragma unroll
        for (int off = 32; off; off >>= 1) {
            const double ov = __shfl_xor(bv, off, 64);
            const int    op = __shfl_xor(bp, off, 64);
            if (ov < bv || (ov == bv && op < bp)) { bv = ov; bp = op; }
        }
        if (lane == 0) idxbuf[(set * NC + c) * NTOK + tok] = bp;
    }
}

// ------------------------------------------------------------------
// Kernel 3: per-token gather + t[r] + out[d]. One block per token.
// ------------------------------------------------------------------
__global__ __launch_bounds__(256) void k_combine(
    const float* __restrict__ x,
    const float* __restrict__ vals_A, const float* __restrict__ vals_B,
    const int* __restrict__ idxbuf, float* __restrict__ out)
{
    __shared__ float xsh[1032];
    __shared__ float part[256];
    __shared__ float tsh[8];
    __shared__ int sIA[64];
    __shared__ int sIB[64];

    const int tid = threadIdx.x;
    const int tok = blockIdx.x;

    if (tid < 64) {
        sIA[tid] = idxbuf[tid * NTOK + tok];
        sIB[tid] = idxbuf[(NC + tid) * NTOK + tok];
    }
    {
        const float4 v = *(const float4*)(x + (size_t)tok * DMODEL + tid * 4);
        const int base = tid * 4 + (tid >> 5);
        xsh[base + 0] = v.x;
        xsh[base + 1] = v.y;
        xsh[base + 2] = v.z;
        xsh[base + 3] = v.w;
    }
    __syncthreads();
    {
        const int c = tid & 63, mseg = tid >> 6;
        const int ia = sIA[c];
        const float4* va = (const float4*)(vals_A + (size_t)(c * NP + ia) * NM + mseg * 32);
        const float* xb = xsh + (c & 7) * 129 + mseg * 32;
        float s = 0.f;
        #pragma unroll
        for (int i = 0; i < 8; ++i) {
            const float4 v = va[i];
            s = fmaf(v.x, xb[i * 4 + 0], s);
            s = fmaf(v.y, xb[i * 4 + 1], s);
            s = fmaf(v.z, xb[i * 4 + 2], s);
            s = fmaf(v.w, xb[i * 4 + 3], s);
        }
        part[tid] = s;
    }
    __syncthreads();
    if (tid < 8) {
        float s = 0.f;
        #pragma unroll
        for (int m = 0; m < 4; ++m)
            #pragma unroll
            for (int j = 0; j < 8; ++j)
                s += part[m * 64 + tid * 8 + j];
        tsh[tid] = s;
    }
    __syncthreads();
    {
        const int d0 = tid * 4, dblk = tid >> 5, dm = d0 & 127;
        float o0 = 0.f, o1 = 0.f, o2 = 0.f, o3 = 0.f;
        #pragma unroll
        for (int r = 0; r < 8; ++r) {
            const int cb = 8 * r + dblk;
            const int ib = sIB[cb];
            const float4 v = *(const float4*)(vals_B + (size_t)(cb * NP + ib) * NM + dm);
            const float tv = tsh[r];
            o0 = fmaf(tv, v.x, o0);
            o1 = fmaf(tv, v.y, o1);
            o2 = fmaf(tv, v.z, o2);
            o3 = fmaf(tv, v.w, o3);
        }
        *(float4*)(out + (size_t)tok * DMODEL + d0) = make_float4(o0, o1, o2, o3);
    }
}

extern "C" void kernel_launch(void* const* d_in, const int* in_sizes, int n_in,
                              void* d_out, int out_size, void* d_ws, size_t ws_size,
                              hipStream_t stream)
{
    const float* x      = (const float*)d_in[0];
    const float* W_A    = (const float*)d_in[1];
    const float* emb_A  = (const float*)d_in[2];
    const float* vals_A = (const float*)d_in[3];
    const float* W_B    = (const float*)d_in[4];
    const float* emb_B  = (const float*)d_in[5];
    const float* vals_B = (const float*)d_in[6];
    float* out = (float*)d_out;

    // ws: cnt 16B | list 1MB | idxbuf 4MB | xh 16MB | xl 16MB | whA/wlA/whB/wlB 2MB each
    char* w = (char*)d_ws;
    int*   cnt    = (int*)w;
    int*   list   = (int*)(w + 16);
    int*   idxbuf = (int*)(w + 16 + sizeof(int) * (size_t)LCAP);
    size_t off = 16 + sizeof(int) * (size_t)LCAP + sizeof(int) * (size_t)(2 * NC * NTOK);
    short* xh  = (short*)(w + off); off += (size_t)NTOK * DMODEL * 2;
    short* xl  = (short*)(w + off); off += (size_t)NTOK * DMODEL * 2;
    short* whA = (short*)(w + off); off += (size_t)1024 * DMODEL * 2;
    short* wlA = (short*)(w + off); off += (size_t)1024 * DMODEL * 2;
    short* whB = (short*)(w + off); off += (size_t)1024 * DMODEL * 2;
    short* wlB = (short*)(w + off);

    hipMemsetAsync(cnt, 0, sizeof(int), stream);
    k_split<<<5120, 256, 0, stream>>>(x, W_A, W_B, xh, xl, whA, wlA, whB, wlB);
    k_mfma_argmin<<<256, 512, 0, stream>>>(xh, xl, whA, wlA, whB, wlB,
                                           emb_A, emb_B, idxbuf, list, cnt);
    k_refine<<<1024, 256, 0, stream>>>(x, W_A, W_B, emb_A, emb_B, list, cnt, idxbuf);
    k_combine<<<NTOK, 256, 0, stream>>>(x, vals_A, vals_B, idxbuf, out);
}